// Round 6
// baseline (213.958 us; speedup 1.0000x reference)
//
#include <hip/hip_runtime.h>

#define NTOK 65536
#define DIM 256
#define KC 1024
#define EPS 0.08f

typedef __attribute__((ext_vector_type(8))) _Float16 f16x8;
typedef __attribute__((ext_vector_type(8))) unsigned short u16x8;
typedef __attribute__((ext_vector_type(4))) float f32x4;

static __device__ __forceinline__ unsigned short f16bits(float f) {
  _Float16 h = (_Float16)f;
  return __builtin_bit_cast(unsigned short, h);
}

// ---- e: fp32 -> fp16 FRAGMENT-MAJOR global image + esq; zero hist/fix ----
// Chunk c = ct*64 + s*8 + nj (1 KB each): 64 lanes x 16 B, lane = kq*16+col
// holds e[ct*128 + nj*16 + col][s*32 + kq*8 + j], j=0..7, as 8 f16.
// Thread (t, o): row t, octet o (k = o*8..o*8+7): s = o>>2, kq = o&3.
__global__ __launch_bounds__(256) void vq_prep_e(const float* __restrict__ e,
                                                 unsigned short* __restrict__ eg,
                                                 float* __restrict__ esq,
                                                 int* __restrict__ hist,
                                                 int* __restrict__ fixCount) {
  const int gid = blockIdx.x * 256 + threadIdx.x;  // 32768 work items
  const int t = gid >> 5;   // code row 0..1023
  const int o = gid & 31;   // k-octet 0..31
  const float4 v0 = *reinterpret_cast<const float4*>(&e[t * DIM + o * 8]);
  const float4 v1 = *reinterpret_cast<const float4*>(&e[t * DIM + o * 8 + 4]);
  u16x8 u;
  u[0] = f16bits(v0.x); u[1] = f16bits(v0.y); u[2] = f16bits(v0.z); u[3] = f16bits(v0.w);
  u[4] = f16bits(v1.x); u[5] = f16bits(v1.y); u[6] = f16bits(v1.z); u[7] = f16bits(v1.w);
  const int ct = t >> 7, nj = (t >> 4) & 7, col = t & 15;
  const int s = o >> 2, kq = o & 3;
  char* dst = (char*)eg + ((ct * 64 + s * 8 + nj) << 10) + ((kq * 16 + col) << 4);
  *reinterpret_cast<u16x8*>(dst) = u;
  // esq: reduce over the 32 octet-lanes of this row (lanes 0-31 / 32-63 are
  // distinct rows; xor masks <=16 never cross the 32-lane halves)
  float p = v0.x * v0.x + v0.y * v0.y + v0.z * v0.z + v0.w * v0.w +
            v1.x * v1.x + v1.y * v1.y + v1.z * v1.z + v1.w * v1.w;
#pragma unroll
  for (int m = 16; m > 0; m >>= 1) p += __shfl_xor(p, m, 64);
  if (o == 0) esq[t] = p;
  if (blockIdx.x < 4) hist[blockIdx.x * 256 + threadIdx.x] = 0;
  if (gid == 0) *fixCount = 0;
}

// ---- fused: x-in-regs, B direct-from-L2 (no LDS tiles, NO barriers) ----
__global__ __launch_bounds__(256, 2) void vq_argmin_fused(
    const float* __restrict__ x, const unsigned short* __restrict__ eg,
    const float* __restrict__ e, const float* __restrict__ esq,
    float* __restrict__ outIdxF, float* __restrict__ outQ,
    float* __restrict__ bestDist, float* __restrict__ xsq,
    int* __restrict__ hist, int* __restrict__ fixCount,
    int* __restrict__ fixList) {
  __shared__ int fidx[128];  // wave-local segments; no cross-wave access

  const int tid = threadIdx.x, lane = tid & 63, w = tid >> 6;
  const int col = lane & 15, kq = lane >> 4;
  const int tw = blockIdx.x * 128 + w * 32;  // this wave's 32 tokens

  // -- prologue: x -> registers in A-fragment layout; per-token xsq --
  // lane holds x[tw + m*16 + col][s*32 + kq*8 + j], j=0..7, as f16
  f16x8 a[2][8];
  float sqm[2] = {0.f, 0.f};
#pragma unroll
  for (int m = 0; m < 2; ++m) {
#pragma unroll
    for (int s = 0; s < 8; ++s) {
      const float* xp = &x[(tw + m * 16 + col) * DIM + s * 32 + kq * 8];
      const float4 v0 = *reinterpret_cast<const float4*>(xp);
      const float4 v1 = *reinterpret_cast<const float4*>(xp + 4);
      a[m][s][0] = (_Float16)v0.x; a[m][s][1] = (_Float16)v0.y;
      a[m][s][2] = (_Float16)v0.z; a[m][s][3] = (_Float16)v0.w;
      a[m][s][4] = (_Float16)v1.x; a[m][s][5] = (_Float16)v1.y;
      a[m][s][6] = (_Float16)v1.z; a[m][s][7] = (_Float16)v1.w;
      sqm[m] += v0.x * v0.x + v0.y * v0.y + v0.z * v0.z + v0.w * v0.w +
                v1.x * v1.x + v1.y * v1.y + v1.z * v1.z + v1.w * v1.w;
    }
  }
#pragma unroll
  for (int m = 0; m < 2; ++m) {
    sqm[m] += __shfl_xor(sqm[m], 16, 64);
    sqm[m] += __shfl_xor(sqm[m], 32, 64);
  }
  if (lane < 16) {
    xsq[tw + lane] = sqm[0];
    xsq[tw + 16 + lane] = sqm[1];
  }

  float best[2][4], second[2][4];
  int bidx[2][4];
#pragma unroll
  for (int mi = 0; mi < 2; ++mi)
#pragma unroll
    for (int r = 0; r < 4; ++r) {
      best[mi][r] = 3.4e38f; second[mi][r] = 3.4e38f; bidx[mi][r] = 0;
    }

  for (int ct = 0; ct < 8; ++ct) {
    const char* ebase = (const char*)eg + ct * 65536;
    f32x4 acc[2][8];
#pragma unroll
    for (int mi = 0; mi < 2; ++mi)
#pragma unroll
      for (int nj = 0; nj < 8; ++nj) acc[mi][nj] = (f32x4){0.f, 0.f, 0.f, 0.f};

#pragma unroll
    for (int s = 0; s < 8; ++s) {
      f16x8 b[8];
#pragma unroll
      for (int nj = 0; nj < 8; ++nj)
        b[nj] = *reinterpret_cast<const f16x8*>(
            ebase + ((s * 8 + nj) << 10) + (lane << 4));
#pragma unroll
      for (int mi = 0; mi < 2; ++mi)
#pragma unroll
        for (int nj = 0; nj < 8; ++nj)
          acc[mi][nj] = __builtin_amdgcn_mfma_f32_16x16x32_f16(
              a[mi][s], b[nj], acc[mi][nj], 0, 0, 0);
    }

    // distances for this 128-code chunk; codes ascend per lane over (ct, nj)
#pragma unroll
    for (int nj = 0; nj < 8; ++nj) {
      const int code = ct * 128 + nj * 16 + col;
      const float sqv = esq[code];
#pragma unroll
      for (int mi = 0; mi < 2; ++mi)
#pragma unroll
        for (int r = 0; r < 4; ++r) {
          const float d = fmaf(-2.f, acc[mi][nj][r], sqv);
          if (d < best[mi][r]) {
            second[mi][r] = best[mi][r];
            best[mi][r] = d;
            bidx[mi][r] = code;
          } else if (d < second[mi][r]) {
            second[mi][r] = d;
          }
        }
    }
  }

  // wave-local cross-lane reduce over the 16 code-columns
#pragma unroll
  for (int mi = 0; mi < 2; ++mi)
#pragma unroll
    for (int r = 0; r < 4; ++r) {
      float b = best[mi][r], s2 = second[mi][r];
      int bi = bidx[mi][r];
#pragma unroll
      for (int m = 1; m <= 8; m <<= 1) {
        const float ob = __shfl_xor(b, m, 64);
        const float os = __shfl_xor(s2, m, 64);
        const int   oi = __shfl_xor(bi, m, 64);
        s2 = fminf(fminf(s2, os), fmaxf(b, ob));
        if (ob < b || (ob == b && oi < bi)) { b = ob; bi = oi; }
      }
      if (col == 0) {
        const int tl = w * 32 + mi * 16 + kq * 4 + r;
        const int t = tw + mi * 16 + kq * 4 + r;
        outIdxF[t] = (float)bi;
        bestDist[t] = b;
        fidx[tl] = bi;
        atomicAdd(&hist[bi], 1);
        if (s2 - b < EPS) {
          const int p = atomicAdd(fixCount, 1);
          fixList[p] = t;
        }
      }
    }

  // fused gather: wave reads ONLY its own fidx segment (no barrier needed)
  for (int i = 0; i < 32; ++i) {
    const int id = fidx[w * 32 + i];
    const float4 q = reinterpret_cast<const float4*>(&e[id * DIM])[lane];
    reinterpret_cast<float4*>(&outQ[(tw + i) * DIM])[lane] = q;
  }
}

// ---- exact fp32 rescan for near-tie tokens; patch idx/hist/outQ/dist ----
__global__ __launch_bounds__(256) void vq_fixup(
    const float* __restrict__ x, const float* __restrict__ e,
    const float* __restrict__ esq, const int* __restrict__ fixCount,
    const int* __restrict__ fixList, float* __restrict__ outIdxF,
    float* __restrict__ bestDist, float* __restrict__ outQ,
    int* __restrict__ hist) {
  const int n = *fixCount;
  __shared__ float xrow[256];
  __shared__ float rv[4];
  __shared__ int ri[4];
  __shared__ int sOld, sFi;
  const int tid = threadIdx.x;
  for (int it = blockIdx.x; it < n; it += gridDim.x) {
    const int t = fixList[it];
    __syncthreads();
    if (tid < 64) ((float4*)xrow)[tid] = ((const float4*)&x[t * DIM])[tid];
    __syncthreads();
    float bv = 3.4e38f; int bi = 0;
    for (int c = tid; c < KC; c += 256) {
      float s = 0.f;
#pragma unroll
      for (int d = 0; d < DIM; d += 4) {
        const float4 ev = *(const float4*)&e[c * DIM + d];
        s = fmaf(xrow[d], ev.x, s);
        s = fmaf(xrow[d + 1], ev.y, s);
        s = fmaf(xrow[d + 2], ev.z, s);
        s = fmaf(xrow[d + 3], ev.w, s);
      }
      const float dist = fmaf(-2.f, s, esq[c]);
      if (dist < bv) { bv = dist; bi = c; }  // c ascends per thread
    }
#pragma unroll
    for (int m = 1; m <= 32; m <<= 1) {
      const float ob = __shfl_xor(bv, m, 64);
      const int oi = __shfl_xor(bi, m, 64);
      if (ob < bv || (ob == bv && oi < bi)) { bv = ob; bi = oi; }
    }
    const int lane = tid & 63, wv = tid >> 6;
    if (lane == 0) { rv[wv] = bv; ri[wv] = bi; }
    __syncthreads();
    if (tid == 0) {
      float fb = rv[0]; int fi = ri[0];
      for (int k = 1; k < 4; ++k)
        if (rv[k] < fb || (rv[k] == fb && ri[k] < fi)) { fb = rv[k]; fi = ri[k]; }
      sOld = (int)outIdxF[t];
      sFi = fi;
      bestDist[t] = fb;  // exact distance for loss
      if (fi != sOld) {
        atomicSub(&hist[sOld], 1);
        atomicAdd(&hist[fi], 1);
        outIdxF[t] = (float)fi;
      }
    }
    __syncthreads();
    if (sFi != sOld) outQ[t * DIM + tid] = e[sFi * DIM + tid];
    __syncthreads();
  }
}

// ---- final scalars: loss from xsq+bestDist; perplexity from hist ----
__global__ __launch_bounds__(1024) void vq_final(
    const int* __restrict__ hist, const float* __restrict__ xsq,
    const float* __restrict__ bestDist, float* __restrict__ outLoss,
    float* __restrict__ outPerp) {
  const int tid = threadIdx.x;
  float ls = 0.f;
  for (int i = 0; i < 64; ++i) {
    const int t = tid + i * 1024;
    ls += xsq[t] + bestDist[t];
  }
  const float p = (float)hist[tid] * (1.f / 65536.f);
  float ent = p * logf(p + 1e-10f);
#pragma unroll
  for (int o = 32; o > 0; o >>= 1) {
    ls += __shfl_down(ls, o, 64);
    ent += __shfl_down(ent, o, 64);
  }
  __shared__ float lbuf[16], ebuf[16];
  const int lane = tid & 63, wv = tid >> 6;
  if (lane == 0) { lbuf[wv] = ls; ebuf[wv] = ent; }
  __syncthreads();
  if (tid == 0) {
    float L = 0.f, E = 0.f;
    for (int i = 0; i < 16; ++i) { L += lbuf[i]; E += ebuf[i]; }
    *outLoss = 0.25f * (L / 16777216.f);
    *outPerp = expf(-E);
  }
}

extern "C" void kernel_launch(void* const* d_in, const int* in_sizes, int n_in,
                              void* d_out, int out_size, void* d_ws, size_t ws_size,
                              hipStream_t stream) {
  const float* x = (const float*)d_in[0];  // [65536, 256]
  const float* e = (const float*)d_in[1];  // [1024, 256]
  float* out = (float*)d_out;
  float* outQ = out;                 // 16777216 floats
  float* outLoss = out + 16777216;
  float* outPerp = out + 16777217;
  float* outIdxF = out + 16777218;   // 65536 floats

  char* ws = (char*)d_ws;
  int*   hist     = (int*)ws;                    // 4096 B
  float* esq      = (float*)(ws + 4096);         // 4096 B
  float* xsq      = (float*)(ws + 8192);         // 262144 B
  float* bestDist = (float*)(ws + 270336);       // 262144 B
  int*   fixCount = (int*)(ws + 532480);         // 16 B
  int*   fixList  = (int*)(ws + 532496);         // 262144 B (+pad)
  unsigned short* e_f16 = (unsigned short*)(ws + 794640);  // 524288 B

  vq_prep_e<<<128, 256, 0, stream>>>(e, e_f16, esq, hist, fixCount);
  vq_argmin_fused<<<NTOK / 128, 256, 0, stream>>>(
      x, e_f16, e, esq, outIdxF, outQ, bestDist, xsq, hist, fixCount, fixList);
  vq_fixup<<<256, 256, 0, stream>>>(x, e, esq, fixCount, fixList, outIdxF,
                                    bestDist, outQ, hist);
  vq_final<<<1, 1024, 0, stream>>>(hist, xsq, bestDist, outLoss, outPerp);
}